// Round 1
// baseline (1370.521 us; speedup 1.0000x reference)
//
#include <hip/hip_runtime.h>
#include <math.h>

#define B_Q     1024
#define DIM     128
#define N_KEYS  100000
#define N_CLS   1000
#define BETA    8.0f
#define BQ      16      // queries per block
#define BK      32      // keys staged per iteration
#define KCHUNKS 8       // key chunks -> grid.y
#define THREADS 256

// ---------------- norms: 1/max(||row||, eps), wave per row ----------------
__global__ void hopfield_norms(const float* __restrict__ qm, const float* __restrict__ km,
                               float* __restrict__ rnq, float* __restrict__ rnk) {
    const int gid  = blockIdx.x * blockDim.x + threadIdx.x;
    const int wid  = gid >> 6;
    const int lane = gid & 63;
    if (wid >= B_Q + N_KEYS) return;
    const float* src = (wid < B_Q) ? (qm + (size_t)wid * DIM)
                                   : (km + (size_t)(wid - B_Q) * DIM);
    const float a = src[lane];
    const float b = src[lane + 64];
    float ss = a * a + b * b;
    #pragma unroll
    for (int o = 32; o >= 1; o >>= 1) ss += __shfl_xor(ss, o);
    if (lane == 0) {
        const float rn = 1.0f / fmaxf(sqrtf(ss), 1e-12f);
        if (wid < B_Q) rnq[wid] = rn; else rnk[wid - B_Q] = rn;
    }
}

// ---------------- main: sims -> exp -> per-class LDS accumulation ----------------
// thread decomposition: ds = d-slice (4 x 32 dims), kl = key lane (8 keys/pass),
// qp = query pair (8 pairs -> 16 queries). 4 threads (ds) cooperate per (q,k) dot.
__global__ __launch_bounds__(THREADS, 2)
void hopfield_main(const float* __restrict__ qm, const float* __restrict__ km,
                   const int* __restrict__ labels,
                   const float* __restrict__ rnq, const float* __restrict__ rnk,
                   float* __restrict__ out) {
    __shared__ float acc[BQ * N_CLS];        // 62.5 KB class buckets
    __shared__ float klds[BK][DIM + 4];      // padded key tile, pre-scaled by 1/||k||
    __shared__ int   llab[BK];

    const int tid = threadIdx.x;
    const int qt  = blockIdx.x;              // query tile 0..63
    const int kc  = blockIdx.y;              // key chunk 0..7

    for (int i = tid; i < BQ * N_CLS; i += THREADS) acc[i] = 0.0f;

    const int ds = tid & 3;
    const int kl = (tid >> 2) & 7;
    const int qp = tid >> 5;
    const int q0 = qt * BQ + qp * 2;

    // per-thread query slices (pre-scaled by 1/||q||), kept in registers
    float qa[32], qb[32];
    {
        const float r0 = rnq[q0], r1 = rnq[q0 + 1];
        const float* p0 = qm + (size_t)q0 * DIM + ds * 32;
        const float* p1 = p0 + DIM;
        #pragma unroll
        for (int j = 0; j < 32; ++j) { qa[j] = p0[j] * r0; qb[j] = p1[j] * r1; }
    }

    const int nbeg = kc * (N_KEYS / KCHUNKS);
    const int nend = nbeg + (N_KEYS / KCHUNKS);

    for (int nb = nbeg; nb < nend; nb += BK) {
        const int kn = min(BK, nend - nb);
        __syncthreads();                      // protect klds reuse
        // stage kn keys, scaled by 1/||k||
        for (int t = tid; t < kn * (DIM / 4); t += THREADS) {
            const int row = t >> 5;
            const int col = t & 31;
            const int n   = nb + row;
            float4 v = *(const float4*)(km + (size_t)n * DIM + col * 4);
            const float s = rnk[n];
            v.x *= s; v.y *= s; v.z *= s; v.w *= s;
            *(float4*)(&klds[row][col * 4]) = v;
        }
        if (tid < kn) llab[tid] = labels[nb + tid];
        __syncthreads();

        #pragma unroll
        for (int pass = 0; pass < BK / 8; ++pass) {
            const int krow = pass * 8 + kl;
            float d0 = 0.0f, d1 = 0.0f;
            const float* kp = &klds[krow][ds * 32];
            #pragma unroll
            for (int j = 0; j < 8; ++j) {
                const float4 kv = *(const float4*)(kp + j * 4);
                d0 = fmaf(qa[j*4+0], kv.x, d0);
                d0 = fmaf(qa[j*4+1], kv.y, d0);
                d0 = fmaf(qa[j*4+2], kv.z, d0);
                d0 = fmaf(qa[j*4+3], kv.w, d0);
                d1 = fmaf(qb[j*4+0], kv.x, d1);
                d1 = fmaf(qb[j*4+1], kv.y, d1);
                d1 = fmaf(qb[j*4+2], kv.z, d1);
                d1 = fmaf(qb[j*4+3], kv.w, d1);
            }
            // combine the 4 d-slices (lanes differing in bits 0-1)
            d0 += __shfl_xor(d0, 1); d0 += __shfl_xor(d0, 2);
            d1 += __shfl_xor(d1, 1); d1 += __shfl_xor(d1, 2);
            if (ds == 0 && krow < kn) {
                const int lab = llab[krow];
                atomicAdd(&acc[(qp * 2    ) * N_CLS + lab], __expf(BETA * d0));
                atomicAdd(&acc[(qp * 2 + 1) * N_CLS + lab], __expf(BETA * d1));
            }
        }
    }

    __syncthreads();
    // flush block-local buckets to global (8 chunk-blocks contend per cell)
    float* obase = out + (size_t)qt * BQ * N_CLS;
    for (int i = tid; i < BQ * N_CLS; i += THREADS) {
        atomicAdd(&obase[i], acc[i]);
    }
}

// ---------------- normalize each output row by its sum ----------------
__global__ void hopfield_norm_out(float* __restrict__ out) {
    const int b = blockIdx.x;
    __shared__ float wsum[4];
    float* row = out + (size_t)b * N_CLS;
    float s = 0.0f;
    for (int i = threadIdx.x; i < N_CLS; i += THREADS) s += row[i];
    #pragma unroll
    for (int o = 32; o >= 1; o >>= 1) s += __shfl_xor(s, o);
    const int wid = threadIdx.x >> 6;
    if ((threadIdx.x & 63) == 0) wsum[wid] = s;
    __syncthreads();
    const float total = wsum[0] + wsum[1] + wsum[2] + wsum[3];
    const float inv = 1.0f / total;
    for (int i = threadIdx.x; i < N_CLS; i += THREADS) row[i] *= inv;
}

extern "C" void kernel_launch(void* const* d_in, const int* in_sizes, int n_in,
                              void* d_out, int out_size, void* d_ws, size_t ws_size,
                              hipStream_t stream) {
    const float* qm     = (const float*)d_in[0];
    const float* km     = (const float*)d_in[1];
    const int*   labels = (const int*)d_in[2];
    float* out = (float*)d_out;
    float* rnq = (float*)d_ws;          // [1024]
    float* rnk = rnq + B_Q;             // [100000]

    hipMemsetAsync(d_out, 0, (size_t)B_Q * N_CLS * sizeof(float), stream);

    const int totalRows = B_Q + N_KEYS;
    const int nblk = (totalRows * 64 + THREADS - 1) / THREADS;
    hipLaunchKernelGGL(hopfield_norms, dim3(nblk), dim3(THREADS), 0, stream,
                       qm, km, rnq, rnk);

    dim3 grid(B_Q / BQ, KCHUNKS);
    hipLaunchKernelGGL(hopfield_main, grid, dim3(THREADS), 0, stream,
                       qm, km, labels, rnq, rnk, out);

    hipLaunchKernelGGL(hopfield_norm_out, dim3(B_Q), dim3(THREADS), 0, stream, out);
}

// Round 2
// 563.313 us; speedup vs baseline: 2.4330x; 2.4330x over previous
//
#include <hip/hip_runtime.h>
#include <math.h>

typedef _Float16 f16;
typedef _Float16 f16x8 __attribute__((ext_vector_type(8)));
typedef float    f32x16 __attribute__((ext_vector_type(16)));

#define B_Q     1024
#define DIM     128
#define N_KEYS  100000
#define N_CLS   1000
#define BQ      32                  // queries per block (acc LDS = 128 KB)
#define KCHUNK  8                   // key chunks (one per XCD)
#define CHUNK   (N_KEYS / KCHUNK)   // 12500
#define KT      256                 // keys per block iteration (8 waves x 32)
#define THREADS 512
#define QSCALE  11.541560327111707f /* 8 / ln(2): fold beta*log2(e) into q */

// ---- preprocess: L2-normalize rows, scale, convert to f16 (one wave/row) ----
__global__ void prep_rows(const float* __restrict__ src, f16* __restrict__ dst,
                          int nrows, float scale) {
    const int gid  = blockIdx.x * blockDim.x + threadIdx.x;
    const int wid  = gid >> 6;
    const int lane = threadIdx.x & 63;
    if (wid >= nrows) return;
    const float* row = src + (size_t)wid * DIM;
    const float a = row[lane];
    const float b = row[lane + 64];
    float ss = a * a + b * b;
    #pragma unroll
    for (int o = 32; o >= 1; o >>= 1) ss += __shfl_xor(ss, o);
    const float rn = scale / fmaxf(sqrtf(ss), 1e-12f);
    f16* drow = dst + (size_t)wid * DIM;
    drow[lane]      = (f16)(a * rn);
    drow[lane + 64] = (f16)(b * rn);
}

// ---- main: MFMA sims -> exp2 -> LDS class buckets -> global atomic flush ----
// Each wave: 32q x 32k tile via v_mfma_f32_32x32x16_f16, K=128 (8 mfma).
// A frag (queries, regs, loaded once): lane row = l&31, k = kk*16 + (l>>5)*8.
// B frag (keys, global->regs each iter): lane col = l&31, same k pattern.
// C/D: col(key)=lane&31, row(q) = (r&3) + 8*(r>>2) + 4*(lane>>5).
__global__ __launch_bounds__(THREADS, 2)
void hopfield_mfma(const f16* __restrict__ kf, const f16* __restrict__ qf,
                   const int* __restrict__ labels, float* __restrict__ out) {
    __shared__ float acc[BQ * N_CLS];   // 128000 B class buckets

    const int tid  = threadIdx.x;
    const int kc   = blockIdx.x;        // chunk: fast dim -> pins to one XCD
    const int qt   = blockIdx.y;        // query tile
    const int wid  = tid >> 6;
    const int lane = tid & 63;
    const int l31  = lane & 31;
    const int lhi  = lane >> 5;

    for (int i = tid; i < BQ * N_CLS; i += THREADS) acc[i] = 0.0f;

    // A fragments: all waves share the same 32 queries
    f16x8 a[8];
    {
        const f16* qbase = qf + (size_t)(qt * BQ + l31) * DIM + lhi * 8;
        #pragma unroll
        for (int kk = 0; kk < 8; ++kk) a[kk] = *(const f16x8*)(qbase + kk * 16);
    }
    __syncthreads();                    // acc init visible to all waves

    const int nbeg = kc * CHUNK;
    const int nit  = (CHUNK + KT - 1) / KT;   // 49

#define LOADB(B, LBL, T) {                                                   \
        const int rel = (T) * KT + wid * 32 + l31;                           \
        const int n   = nbeg + min(rel, CHUNK - 1);                          \
        const f16* kb = kf + (size_t)n * DIM + lhi * 8;                      \
        _Pragma("unroll")                                                    \
        for (int kk = 0; kk < 8; ++kk) B[kk] = *(const f16x8*)(kb + kk * 16);\
        LBL = labels[n];                                                     \
    }

#define COMPUTE(B, LBL, T) {                                                 \
        f32x16 c = {};                                                       \
        _Pragma("unroll")                                                    \
        for (int kk = 0; kk < 8; ++kk)                                       \
            c = __builtin_amdgcn_mfma_f32_32x32x16_f16(a[kk], B[kk], c, 0, 0, 0); \
        const int rel = (T) * KT + wid * 32 + l31;                           \
        if (rel < CHUNK) {                                                   \
            _Pragma("unroll")                                                \
            for (int r = 0; r < 16; ++r) {                                   \
                const int row = (r & 3) + 8 * (r >> 2) + 4 * lhi;            \
                const float w = __builtin_amdgcn_exp2f(c[r]);                \
                atomicAdd(&acc[row * N_CLS + LBL], w);                       \
            }                                                                \
        }                                                                    \
    }

    f16x8 Ba[8], Bb[8];
    int la, lb;
    LOADB(Ba, la, 0);
    int t = 0;
    for (; t + 2 <= nit; t += 2) {
        LOADB(Bb, lb, t + 1);
        COMPUTE(Ba, la, t);
        if (t + 2 < nit) LOADB(Ba, la, t + 2);
        COMPUTE(Bb, lb, t + 1);
    }
    if (t < nit) COMPUTE(Ba, la, t);    // nit odd -> last tile in Ba

#undef LOADB
#undef COMPUTE

    __syncthreads();                    // all accumulation done
    float* ob = out + (size_t)qt * BQ * N_CLS;
    for (int i = tid; i < BQ * N_CLS; i += THREADS) {
        const float v = acc[i];
        if (v != 0.0f) atomicAdd(&ob[i], v);
    }
}

// ---- normalize each output row by its sum (softmax denominator) ----
__global__ void hopfield_norm_out(float* __restrict__ out) {
    const int b = blockIdx.x;
    __shared__ float wsum[4];
    float* row = out + (size_t)b * N_CLS;
    float s = 0.0f;
    for (int i = threadIdx.x; i < N_CLS; i += 256) s += row[i];
    #pragma unroll
    for (int o = 32; o >= 1; o >>= 1) s += __shfl_xor(s, o);
    const int wv = threadIdx.x >> 6;
    if ((threadIdx.x & 63) == 0) wsum[wv] = s;
    __syncthreads();
    const float inv = 1.0f / (wsum[0] + wsum[1] + wsum[2] + wsum[3]);
    for (int i = threadIdx.x; i < N_CLS; i += 256) row[i] *= inv;
}

extern "C" void kernel_launch(void* const* d_in, const int* in_sizes, int n_in,
                              void* d_out, int out_size, void* d_ws, size_t ws_size,
                              hipStream_t stream) {
    const float* qm     = (const float*)d_in[0];
    const float* km     = (const float*)d_in[1];
    const int*   labels = (const int*)d_in[2];
    float* out = (float*)d_out;

    f16* kf = (f16*)d_ws;                       // [100000][128] f16 = 25.6 MB
    f16* qf = kf + (size_t)N_KEYS * DIM;        // [1024][128]  f16 = 0.26 MB

    hipMemsetAsync(d_out, 0, (size_t)B_Q * N_CLS * sizeof(float), stream);

    // keys: scale 1.0; queries: fold beta/ln2
    hipLaunchKernelGGL(prep_rows, dim3((N_KEYS + 7) / 8), dim3(THREADS), 0, stream,
                       km, kf, N_KEYS, 1.0f);
    hipLaunchKernelGGL(prep_rows, dim3((B_Q + 7) / 8), dim3(THREADS), 0, stream,
                       qm, qf, B_Q, QSCALE);

    hipLaunchKernelGGL(hopfield_mfma, dim3(KCHUNK, B_Q / BQ), dim3(THREADS), 0, stream,
                       kf, qf, labels, out);

    hipLaunchKernelGGL(hopfield_norm_out, dim3(B_Q), dim3(256), 0, stream, out);
}

// Round 3
// 136.324 us; speedup vs baseline: 10.0534x; 4.1322x over previous
//
#include <hip/hip_runtime.h>
#include <math.h>

typedef _Float16 f16;
typedef _Float16 f16x8 __attribute__((ext_vector_type(8)));
typedef float    f32x16 __attribute__((ext_vector_type(16)));
typedef unsigned int uint;

#define B_Q     1024
#define DIM     128
#define N_KEYS  100000
#define N_CLS   1000
#define QSCALE  11.541560327111707f /* 8/ln2: fold beta*log2(e) into queries */

// ---- label histogram (LDS-reduced) ----
__global__ void k_hist(const int* __restrict__ labels, uint* __restrict__ ghist) {
    __shared__ uint lh[N_CLS];
    for (int i = threadIdx.x; i < N_CLS; i += blockDim.x) lh[i] = 0;
    __syncthreads();
    const int stride = gridDim.x * blockDim.x;
    for (int i = blockIdx.x * blockDim.x + threadIdx.x; i < N_KEYS; i += stride)
        atomicAdd(&lh[labels[i]], 1u);
    __syncthreads();
    for (int i = threadIdx.x; i < N_CLS; i += blockDim.x)
        if (lh[i]) atomicAdd(&ghist[i], lh[i]);
}

// ---- exclusive scan over 1000 bins (single 1024-thread block) ----
__global__ void k_scan(const uint* __restrict__ ghist, uint* __restrict__ offs,
                       uint* __restrict__ cursor) {
    __shared__ uint s[1024];
    const int t = threadIdx.x;
    const uint v = (t < N_CLS) ? ghist[t] : 0u;
    s[t] = v; __syncthreads();
    for (int o = 1; o < 1024; o <<= 1) {
        const uint x = (t >= o) ? s[t - o] : 0u;
        __syncthreads();
        s[t] += x;
        __syncthreads();
    }
    if (t < N_CLS) { const uint e = s[t] - v; offs[t] = e; cursor[t] = e; }
    if (t == 1023) offs[N_CLS] = s[1023];
}

// ---- counting-sort scatter fused with normalize + f16 convert (1 wave/key) ----
__global__ void k_sortkeys(const float* __restrict__ km, const int* __restrict__ labels,
                           uint* __restrict__ cursor, f16* __restrict__ kf) {
    const int gid  = blockIdx.x * blockDim.x + threadIdx.x;
    const int n    = gid >> 6;
    const int lane = threadIdx.x & 63;
    if (n >= N_KEYS) return;
    const float* row = km + (size_t)n * DIM;
    const float a = row[lane];
    const float b = row[lane + 64];
    float ss = a * a + b * b;
    #pragma unroll
    for (int o = 32; o >= 1; o >>= 1) ss += __shfl_xor(ss, o);
    const float rn = 1.0f / fmaxf(sqrtf(ss), 1e-12f);
    int pos = 0;
    if (lane == 0) pos = (int)atomicAdd(&cursor[labels[n]], 1u);
    pos = __shfl(pos, 0);
    f16* dst = kf + (size_t)pos * DIM;
    dst[lane]      = (f16)(a * rn);
    dst[lane + 64] = (f16)(b * rn);
}

// ---- query prep: normalize, fold QSCALE, f16 (1 wave/row) ----
__global__ void k_prepq(const float* __restrict__ src, f16* __restrict__ dst) {
    const int gid  = blockIdx.x * blockDim.x + threadIdx.x;
    const int wid  = gid >> 6;
    const int lane = threadIdx.x & 63;
    if (wid >= B_Q) return;
    const float* row = src + (size_t)wid * DIM;
    const float a = row[lane];
    const float b = row[lane + 64];
    float ss = a * a + b * b;
    #pragma unroll
    for (int o = 32; o >= 1; o >>= 1) ss += __shfl_xor(ss, o);
    const float rn = QSCALE / fmaxf(sqrtf(ss), 1e-12f);
    f16* drow = dst + (size_t)wid * DIM;
    drow[lane]      = (f16)(a * rn);
    drow[lane + 64] = (f16)(b * rn);
}

// ---- main: per-(class, 256q) block; MFMA sims -> exp2 -> register sums -> store ----
// Wave-tile 32q x 32k, v_mfma_f32_32x32x16_f16, K=128 (8 mfma).
// A: lane row=l&31, k elems = 16*kk + 8*lhi + j.  B: col=l&31, same k.
// C/D: col(key)=l&31, row(q)=(r&3)+8*(r>>2)+4*lhi.
#define SLOT(key, s) ((((s) ^ ((key) & 15)) + 2 * ((key) >> 4)) & 15)
__global__ __launch_bounds__(512, 2)
void class_gemm(const f16* __restrict__ kf, const f16* __restrict__ qf,
                const uint* __restrict__ offs, float* __restrict__ out) {
    __shared__ __align__(16) f16 kt[32 * DIM];   // 8 KB swizzled key tile

    const int tid  = threadIdx.x;
    const int wid  = tid >> 6;
    const int lane = tid & 63;
    const int l31  = lane & 31;
    const int lhi  = lane >> 5;
    const int c    = blockIdx.x;
    const int qt   = blockIdx.y;

    const int beg = (int)offs[c];
    const int end = (int)offs[c + 1];
    const int cnt = end - beg;

    // A fragments (each wave owns 32 queries)
    f16x8 a[8];
    {
        const f16* qb = qf + (size_t)(qt * 256 + wid * 32 + l31) * DIM + lhi * 8;
        #pragma unroll
        for (int kk = 0; kk < 8; ++kk) a[kk] = *(const f16x8*)(qb + kk * 16);
    }

    float sums[16];
    #pragma unroll
    for (int r = 0; r < 16; ++r) sums[r] = 0.0f;

    const int ntiles = (cnt + 31) >> 5;
    for (int t = 0; t < ntiles; ++t) {
        __syncthreads();                       // previous tile's reads complete
        {   // stage: 512 threads = 32 keys x 16 slots of 16B
            const int key = tid >> 4;
            const int s   = tid & 15;
            const int row = min(beg + t * 32 + key, end - 1);
            const f16x8 v = *(const f16x8*)(kf + (size_t)row * DIM + s * 8);
            *(f16x8*)(kt + key * DIM + SLOT(key, s) * 8) = v;
        }
        __syncthreads();

        f32x16 cacc = {};
        #pragma unroll
        for (int kk = 0; kk < 8; ++kk) {
            const f16x8 b = *(const f16x8*)(kt + l31 * DIM + SLOT(l31, lhi + 2 * kk) * 8);
            cacc = __builtin_amdgcn_mfma_f32_32x32x16_f16(a[kk], b, cacc, 0, 0, 0);
        }
        if (t * 32 + l31 < cnt) {
            #pragma unroll
            for (int r = 0; r < 16; ++r)
                sums[r] += __builtin_amdgcn_exp2f(cacc[r]);
        }
    }

    // reduce over the 32 key-columns (bits 0..4 of lane)
    #pragma unroll
    for (int r = 0; r < 16; ++r) {
        float s = sums[r];
        s += __shfl_xor(s, 1);  s += __shfl_xor(s, 2);  s += __shfl_xor(s, 4);
        s += __shfl_xor(s, 8);  s += __shfl_xor(s, 16);
        sums[r] = s;
    }
    if (l31 == 0) {   // lanes 0 and 32 write the two row-halves
        float* ob = out + (size_t)(qt * 256 + wid * 32) * N_CLS + c;
        #pragma unroll
        for (int r = 0; r < 16; ++r) {
            const int row = (r & 3) + 8 * (r >> 2) + 4 * lhi;
            ob[(size_t)row * N_CLS] = sums[r];
        }
    }
}

// ---- normalize each output row by its sum ----
__global__ void hopfield_norm_out(float* __restrict__ out) {
    const int b = blockIdx.x;
    __shared__ float wsum[4];
    float* row = out + (size_t)b * N_CLS;
    float s = 0.0f;
    for (int i = threadIdx.x; i < N_CLS; i += 256) s += row[i];
    #pragma unroll
    for (int o = 32; o >= 1; o >>= 1) s += __shfl_xor(s, o);
    const int wv = threadIdx.x >> 6;
    if ((threadIdx.x & 63) == 0) wsum[wv] = s;
    __syncthreads();
    const float inv = 1.0f / (wsum[0] + wsum[1] + wsum[2] + wsum[3]);
    for (int i = threadIdx.x; i < N_CLS; i += 256) row[i] *= inv;
}

extern "C" void kernel_launch(void* const* d_in, const int* in_sizes, int n_in,
                              void* d_out, int out_size, void* d_ws, size_t ws_size,
                              hipStream_t stream) {
    const float* qm     = (const float*)d_in[0];
    const float* km     = (const float*)d_in[1];
    const int*   labels = (const int*)d_in[2];
    float* out = (float*)d_out;

    f16*  kf     = (f16*)d_ws;                         // [100000][128] f16, class-sorted
    f16*  qf     = kf + (size_t)N_KEYS * DIM;          // [1024][128] f16
    uint* ghist  = (uint*)(qf + (size_t)B_Q * DIM);    // [1000]
    uint* offs   = ghist + N_CLS;                      // [1001]
    uint* cursor = offs + N_CLS + 1;                   // [1000]

    hipMemsetAsync(ghist, 0, N_CLS * sizeof(uint), stream);

    hipLaunchKernelGGL(k_hist, dim3(32), dim3(256), 0, stream, labels, ghist);
    hipLaunchKernelGGL(k_scan, dim3(1), dim3(1024), 0, stream, ghist, offs, cursor);
    hipLaunchKernelGGL(k_sortkeys, dim3((N_KEYS * 64) / 256), dim3(256), 0, stream,
                       km, labels, cursor, kf);
    hipLaunchKernelGGL(k_prepq, dim3((B_Q * 64) / 256), dim3(256), 0, stream, qm, qf);

    hipLaunchKernelGGL(class_gemm, dim3(N_CLS, B_Q / 256), dim3(512), 0, stream,
                       kf, qf, offs, out);

    hipLaunchKernelGGL(hopfield_norm_out, dim3(B_Q), dim3(256), 0, stream, out);
}